// Round 14
// baseline (705.923 us; speedup 1.0000x reference)
//
#include <hip/hip_runtime.h>
#include <hip/hip_bf16.h>
#include <math.h>

// MoE: 8 experts, top-2, H=1024, I=4096, T=2048. f32 in/out, bf16 MFMA inside.
// Round 14: exact r12 (best measured, 338us) with ONE change: launch_bounds
// (256,5) on g1/g2 — r12 ran 3 waves/SIMD (38%) while VGPR(64)/LDS(32KB)
// admit 5 blocks/CU; latency-bound kernels want TLP, not hand pipelining
// (r13's reg-dbuf spilled to scratch: FETCH +90MB, WRITE +54MB, -42us).
constexpr int kNE = 8;
constexpr int kH  = 1024;
constexpr int kI  = 4096;
constexpr int kT  = 2048;
constexpr int kMaxSlots = kT * 2 + kNE * 64;   // 4608
constexpr int kSlotPad  = kMaxSlots + 128;

typedef short bf16x8 __attribute__((ext_vector_type(8)));
typedef float f32x4  __attribute__((ext_vector_type(4)));

__device__ __forceinline__ short f2bf(float f) {
  union { float f; unsigned u; } v; v.f = f;
  unsigned r = v.u + 0x7fffu + ((v.u >> 16) & 1u);   // RNE
  return (short)(r >> 16);
}

__device__ __forceinline__ int cvtpk(float lo, float hi) {
  int r;
  asm("v_cvt_pk_bf16_f32 %0, %1, %2" : "=v"(r) : "v"(lo), "v"(hi));
  return r;
}

__device__ __forceinline__ void gload16(const void* g, void* lds) {
  __builtin_amdgcn_global_load_lds(
      (const __attribute__((address_space(1))) void*)g,
      (__attribute__((address_space(3))) void*)lds, 16, 0, 0);
}

// ================= shared device building blocks ============================

// w2 transpose pair (two 128k x 64n tiles, 32KB LDS). dst: w2t [E][1024][4096].
__device__ __forceinline__ void w2t_pair(
    char* smemraw, int bt, const float* __restrict__ w2s,
    short* __restrict__ w2t) {
  float* tile = (float*)smemraw;
  const int tid = threadIdx.x;
#pragma unroll 1
  for (int s = 0; s < 2; ++s) {
    const int t = bt * 2 + s;                       // 0..4095
    const int e2 = t >> 9;
    const int r = t & 511;
    const int kbT = (r >> 4) * 128;
    const int nbT = (r & 15) * 64;
    const float* src = w2s + ((size_t)e2 * kI + kbT) * kH + nbT;
    if (s) __syncthreads();                         // LDS reuse WAR
#pragma unroll
    for (int p = 0; p < 8; ++p) {
      const int q = p * 256 + tid;
      const int k = q >> 4;
      const int nc = (q & 15) * 4;
      gload16(src + (size_t)k * kH + nc, (char*)tile + q * 16);
    }
    __syncthreads();                                // drains vmcnt
    const int c = tid & 63;
    const int kw = tid >> 6;
    short* drow = w2t + ((size_t)e2 * kH + nbT + c) * kI + kbT;
#pragma unroll
    for (int i = 0; i < 4; ++i) {
      const int kc = kw * 4 + i;
      bf16x8 v;
#pragma unroll
      for (int j = 0; j < 8; ++j) v[j] = f2bf(tile[(kc * 8 + j) * 64 + c]);
      *(bf16x8*)(drow + kc * 8) = v;
    }
  }
}

// g1 fused block: 128m x 128packed, 4 waves, BK=64, 32KB LDS.
// A: hsb bf16 via gload16 (unchanged). B: w1/w3 f32 -> reg cvt -> swizzled Bs.
__device__ __forceinline__ void g1_gemm_block(
    char* smem, int e, int rb, int nb,
    const short* __restrict__ hsb,
    const float* __restrict__ w1s, const float* __restrict__ w3s,
    const int* __restrict__ cnt, const int* __restrict__ off,
    const int* __restrict__ slot_token, short* __restrict__ inter) {
  const int count = cnt[e];
  if (rb * 128 >= count) return;
  const int slot0 = off[e] + rb * 128;
  const int mlim = ((count + 63) & ~63) - rb * 128;

  short* As = (short*)smem;                         // 16KB [row][slot]
  short* Bs = (short*)(smem + 16384);               // 16KB [c][swz slot]
  const int tid = threadIdx.x;
  const int l = tid & 63, w = tid >> 6;
  const int wr = w >> 1, wc = w & 1;

  // ---- A staging map (gload16, source-side swizzle; r5-r12 verified) ----
  const int srow = l >> 3;
  const int sch  = (l & 7) ^ srow;
  const short* aptr[4];
  unsigned sdstA[4];
#pragma unroll
  for (int i = 0; i < 4; ++i) {
    const int q = w * 4 + i;
    const int row = q * 8 + srow;
    int tok = slot_token[slot0 + row]; if (tok < 0) tok = 0;
    aptr[i] = hsb + (size_t)tok * kH + sch * 8;
    sdstA[i] = (unsigned)(q * 1024 + l * 16);
  }

  // ---- B staging map: thread -> 8k x 4 packed-n patch ----
  const int np = tid & 31;            // n-patch: packed cols np*4 .. np*4+3
  const int kp = tid >> 5;            // k-chunk 0..7 (k = kp*8 .. +7)
  const int selB = (np >> 3) & 1;     // 0 = w1, 1 = w3
  const int rcol = nb * 64 + (np >> 4) * 32 + (np & 7) * 4;   // real col base
  const float* bsrc = (selB ? w3s : w1s) +
      (size_t)e * kH * kI + (size_t)(kp * 8) * kI + rcol;
  unsigned bw[4];
#pragma unroll
  for (int j = 0; j < 4; ++j) {
    const int c = np * 4 + j;
    bw[j] = (unsigned)(c * 128 + (((kp ^ (c & 7) ^ ((c >> 3) & 7)) & 7) * 16));
  }

  f32x4 acc[4][4];
#pragma unroll
  for (int mi = 0; mi < 4; ++mi)
#pragma unroll
    for (int ni = 0; ni < 4; ++ni)
#pragma unroll
      for (int r = 0; r < 4; ++r) acc[mi][ni][r] = 0.f;

  const int r16 = l & 15, g = l >> 4;

  for (int t = 0; t < kH / 64; ++t) {
    const int k0 = t * 64;
    // ---- B loads first (f32, coalesced 256B segments) ----
    float4 bv[8];
#pragma unroll
    for (int q2 = 0; q2 < 8; ++q2)
      bv[q2] = *(const float4*)(bsrc + (size_t)(k0 + q2) * kI);
    // ---- A async gloads (stay in flight past the cvt) ----
#pragma unroll
    for (int i = 0; i < 4; ++i)
      gload16(aptr[i] + k0, (char*)As + sdstA[i]);
    // ---- convert 8k x 4n patch -> 4 bf16x8 granules ----
    int4 gi[4];
#define CVT_GRAN(J, SEL)                                     \
    gi[J].x = cvtpk(bv[0].SEL, bv[1].SEL);                   \
    gi[J].y = cvtpk(bv[2].SEL, bv[3].SEL);                   \
    gi[J].z = cvtpk(bv[4].SEL, bv[5].SEL);                   \
    gi[J].w = cvtpk(bv[6].SEL, bv[7].SEL);
    CVT_GRAN(0, x) CVT_GRAN(1, y) CVT_GRAN(2, z) CVT_GRAN(3, w)
#undef CVT_GRAN
    // prev iteration's MFMA completed at loop-end barrier -> safe to write
#pragma unroll
    for (int j = 0; j < 4; ++j)
      *(int4*)((char*)Bs + bw[j]) = gi[j];
    __syncthreads();                  // drains A gloads + ds_writes
#pragma unroll
    for (int kk = 0; kk < 2; ++kk) {
      const int chunk = kk * 4 + g;
      bf16x8 af[4], bf[4];
#pragma unroll
      for (int mi = 0; mi < 4; ++mi) {
        const int m = wr * 64 + mi * 16 + r16;
        af[mi] = *(const bf16x8*)((const char*)As + m * 128 + ((chunk ^ (m & 7)) * 16));
      }
#pragma unroll
      for (int ni = 0; ni < 4; ++ni) {
        const int c = wc * 64 + ni * 16 + r16;
        bf[ni] = *(const bf16x8*)((const char*)Bs +
                   c * 128 + ((chunk ^ (c & 7) ^ ((c >> 3) & 7)) * 16));
      }
#pragma unroll
      for (int mi = 0; mi < 4; ++mi)
#pragma unroll
        for (int ni = 0; ni < 4; ++ni)
          acc[mi][ni] = __builtin_amdgcn_mfma_f32_16x16x32_bf16(
              af[mi], bf[ni], acc[mi][ni], 0, 0, 0);
    }
    __syncthreads();
  }

  const int colb = (nb * 2 + wc) * 32;
#pragma unroll
  for (int mi = 0; mi < 4; ++mi)
#pragma unroll
    for (int r = 0; r < 4; ++r) {
      const int m = wr * 64 + mi * 16 + g * 4 + r;
      if (m < mlim) {
#pragma unroll
        for (int ni = 0; ni < 2; ++ni) {
          float h1 = acc[mi][ni][r];
          float h3 = acc[mi][ni + 2][r];
          float y = h1 / (1.f + expf(-h1)) * h3;
          inter[(size_t)(slot0 + m) * kI + colb + ni * 16 + r16] = f2bf(y);
        }
      }
    }
}

// ========================= small kernels ====================================

__global__ __launch_bounds__(256) void router_convhs_kernel(
    const float* __restrict__ hs, const float* __restrict__ gw,
    int* __restrict__ cnt, int* __restrict__ tok_e, float* __restrict__ tok_w,
    short* __restrict__ hsb) {
  if (blockIdx.x >= kT / 4) {
    const int idx = (blockIdx.x - kT / 4) * 256 + threadIdx.x;
    const float* p = hs + (size_t)idx * 8;
    float4 a = *(const float4*)p;
    float4 b = *(const float4*)(p + 4);
    bf16x8 w;
    w[0] = f2bf(a.x); w[1] = f2bf(a.y); w[2] = f2bf(a.z); w[3] = f2bf(a.w);
    w[4] = f2bf(b.x); w[5] = f2bf(b.y); w[6] = f2bf(b.z); w[7] = f2bf(b.w);
    *(bf16x8*)(hsb + (size_t)idx * 8) = w;
    return;
  }
  const int lane = threadIdx.x & 63;
  const int wid  = threadIdx.x >> 6;
  const int t = blockIdx.x * 4 + wid;
  const float* hrow = hs + (size_t)t * kH;
  float acc[kNE];
#pragma unroll
  for (int e = 0; e < kNE; ++e) acc[e] = 0.f;
  for (int i = lane; i < kH; i += 64) {
    float x = hrow[i];
    float4 g0 = *(const float4*)(gw + (size_t)i * kNE);
    float4 g1 = *(const float4*)(gw + (size_t)i * kNE + 4);
    acc[0] += x * g0.x; acc[1] += x * g0.y; acc[2] += x * g0.z; acc[3] += x * g0.w;
    acc[4] += x * g1.x; acc[5] += x * g1.y; acc[6] += x * g1.z; acc[7] += x * g1.w;
  }
#pragma unroll
  for (int o = 32; o; o >>= 1)
#pragma unroll
    for (int e = 0; e < kNE; ++e) acc[e] += __shfl_xor(acc[e], o);
  if (lane == 0) {
    int e0 = 0;
#pragma unroll
    for (int e = 1; e < kNE; ++e) if (acc[e] > acc[e0]) e0 = e;
    int e1 = (e0 == 0) ? 1 : 0;
#pragma unroll
    for (int e = 0; e < kNE; ++e) if (e != e0 && acc[e] > acc[e1]) e1 = e;
    float d  = acc[e1] - acc[e0];
    float w0 = 1.f / (1.f + expf(d));
    float w1 = 1.f / (1.f + expf(-d));
    atomicAdd(&cnt[e0], 1);
    atomicAdd(&cnt[e1], 1);
    tok_e[t * 2] = e0; tok_e[t * 2 + 1] = e1;
    tok_w[t * 2] = w0; tok_w[t * 2 + 1] = w1;
  }
}

__global__ __launch_bounds__(256) void offsets_kernel(
    const int* __restrict__ cnt, int* __restrict__ off,
    int* __restrict__ slot_token, float* __restrict__ slot_weight) {
  if (threadIdx.x == 0) {
    int o = 0;
#pragma unroll
    for (int e = 0; e < kNE; ++e) { off[e] = o; o += (cnt[e] + 63) & ~63; }
    off[kNE] = o;
  }
  for (int i = threadIdx.x; i < kSlotPad; i += 256) {
    slot_token[i]  = -1;
    slot_weight[i] = 0.f;
  }
}

__global__ __launch_bounds__(256) void assign_kernel(
    const int* __restrict__ tok_e, const float* __restrict__ tok_w,
    const int* __restrict__ off, int* __restrict__ cursor,
    int* __restrict__ slot_token, float* __restrict__ slot_weight,
    int* __restrict__ token_slots) {
  const int t = blockIdx.x * 256 + threadIdx.x;
  if (t >= kT) return;
#pragma unroll
  for (int k = 0; k < 2; ++k) {
    int e = tok_e[t * 2 + k];
    int pos = off[e] + atomicAdd(&cursor[e], 1);
    slot_token[pos]  = t;
    slot_weight[pos] = tok_w[t * 2 + k];
    token_slots[t * 2 + k] = pos;
  }
}

// g1 wrapper: z<8 fused GEMM; z=8,9 w2 transpose ride-along.
__global__ __launch_bounds__(256, 5) void g1_kernel(
    const short* __restrict__ hsb,
    const float* __restrict__ w1s, const float* __restrict__ w3s,
    const int* __restrict__ cnt, const int* __restrict__ off,
    const int* __restrict__ slot_token, short* __restrict__ inter,
    const float* __restrict__ w2s, short* __restrict__ w2t) {
  __shared__ __align__(16) char smem[32768];
  if (blockIdx.z >= 8) {
    w2t_pair(smem, ((blockIdx.z - 8) * 16 + blockIdx.y) * 64 + blockIdx.x,
             w2s, w2t);
    return;
  }
  g1_gemm_block(smem, blockIdx.z, blockIdx.y, blockIdx.x,
                hsb, w1s, w3s, cnt, off, slot_token, inter);
}

// --------- GEMM2: slot_out = w_slot * (inter @ w2), full-K, XCD-swizzled ----
__global__ __launch_bounds__(256, 5) void g2_kernel(
    const short* __restrict__ inter, const short* __restrict__ w2t,
    const int* __restrict__ cnt, const int* __restrict__ off,
    const float* __restrict__ slot_weight, float* __restrict__ slot_out) {
  const int bid = blockIdx.x;
  const int lid = (bid & 7) * 128 + (bid >> 3);
  const int nb = lid & 7;
  const int rb = (lid >> 3) & 15;
  const int e  = lid >> 7;
  const int count = cnt[e];
  if (rb * 128 >= count) return;
  const int slot0 = off[e] + rb * 128;
  const int mlim = ((count + 63) & ~63) - rb * 128;

  __shared__ __align__(16) short As[128 * 64];
  __shared__ __align__(16) short Bs[128 * 64];

  const int tid = threadIdx.x;
  const int l = tid & 63, w = tid >> 6;
  const int wr = w >> 1, wc = w & 1;

  const int srow = l >> 3;
  const int sch  = (l & 7) ^ srow;
  const short* aptr[4];
  const short* bptr[4];
  unsigned sdst[4];
#pragma unroll
  for (int i = 0; i < 4; ++i) {
    const int q = w * 4 + i;
    const int row = q * 8 + srow;
    int sr = slot0 + row; if (sr >= kMaxSlots) sr = kMaxSlots - 1;
    aptr[i] = inter + (size_t)sr * kI + sch * 8;
    bptr[i] = w2t + ((size_t)e * kH + nb * 128 + row) * kI + sch * 8;
    sdst[i] = (unsigned)(q * 1024 + l * 16);
  }

  f32x4 acc[4][4];
#pragma unroll
  for (int mi = 0; mi < 4; ++mi)
#pragma unroll
    for (int ni = 0; ni < 4; ++ni)
#pragma unroll
      for (int r = 0; r < 4; ++r) acc[mi][ni][r] = 0.f;

  const int r16 = l & 15, g = l >> 4;

  for (int t = 0; t < kI / 64; ++t) {
    const int k0 = t * 64;
#pragma unroll
    for (int i = 0; i < 4; ++i) {
      gload16(aptr[i] + k0, (char*)As + sdst[i]);
      gload16(bptr[i] + k0, (char*)Bs + sdst[i]);
    }
    __syncthreads();
#pragma unroll
    for (int kk = 0; kk < 2; ++kk) {
      const int chunk = kk * 4 + g;
      bf16x8 af[4], bf[4];
#pragma unroll
      for (int mi = 0; mi < 4; ++mi) {
        const int m = wr * 64 + mi * 16 + r16;
        af[mi] = *(const bf16x8*)((const char*)As + m * 128 + ((chunk ^ (m & 7)) * 16));
      }
#pragma unroll
      for (int ni = 0; ni < 4; ++ni) {
        const int n = wc * 64 + ni * 16 + r16;
        bf[ni] = *(const bf16x8*)((const char*)Bs + n * 128 + ((chunk ^ (n & 7)) * 16));
      }
#pragma unroll
      for (int mi = 0; mi < 4; ++mi)
#pragma unroll
        for (int ni = 0; ni < 4; ++ni)
          acc[mi][ni] = __builtin_amdgcn_mfma_f32_16x16x32_bf16(
              af[mi], bf[ni], acc[mi][ni], 0, 0, 0);
    }
    __syncthreads();
  }

#pragma unroll
  for (int mi = 0; mi < 4; ++mi)
#pragma unroll
    for (int r = 0; r < 4; ++r) {
      const int m = wr * 64 + mi * 16 + g * 4 + r;
      if (m < mlim) {
        const float sw = slot_weight[slot0 + m];
        const size_t orow = (size_t)(slot0 + m) * kH;
#pragma unroll
        for (int ni = 0; ni < 4; ++ni)
          slot_out[orow + nb * 128 + wc * 64 + ni * 16 + r16] =
              sw * acc[mi][ni][r];
      }
    }
}

// ------- combine: out[t] = slot_out[s0] + slot_out[s1] ----------------------
__global__ __launch_bounds__(256) void combine2_kernel(
    const float* __restrict__ slot_out, const int* __restrict__ token_slots,
    float* __restrict__ out) {
  int idx = blockIdx.x * 256 + threadIdx.x;
  int t = idx >> 8;
  int c = (idx & 255) * 4;
  int s0 = token_slots[t * 2];
  int s1 = token_slots[t * 2 + 1];
  float4 a = *(const float4*)(slot_out + (size_t)s0 * kH + c);
  float4 b = *(const float4*)(slot_out + (size_t)s1 * kH + c);
  float4 o;
  o.x = a.x + b.x; o.y = a.y + b.y; o.z = a.z + b.z; o.w = a.w + b.w;
  *(float4*)(out + (size_t)t * kH + c) = o;
}

// ===================== fallback path (r1, in-loop convert) ==================
__global__ __launch_bounds__(256) void fb_mlp1(
    const float* __restrict__ hs,
    const float* __restrict__ w1s, const float* __restrict__ w3s,
    const int* __restrict__ cnt, const int* __restrict__ off,
    const int* __restrict__ slot_token, short* __restrict__ inter) {
  const int e = blockIdx.z;
  const int count = cnt[e];
  const int rb = blockIdx.y;
  if (rb * 64 >= count) return;
  const int slot0 = off[e] + rb * 64;
  const int nb = blockIdx.x * 128;
  __shared__ __align__(16) short As[4 * 64 * 8];
  __shared__ __align__(16) short Bs[2][4 * 128 * 8];
  const int tid  = threadIdx.x;
  const int lane = tid & 63;
  const int wid  = tid >> 6;
  const int wr = wid >> 1, wc = wid & 1;
  const int am = tid & 63, akb = tid >> 6;
  int tok = slot_token[slot0 + am];
  if (tok < 0) tok = 0;
  const float* arow = hs + (size_t)tok * kH + akb * 8;
  const int which = tid >> 7;
  const int bn0 = (tid & 31) * 4;
  const int bkb = (tid >> 5) & 3;
  const float* wbase = (which ? w3s : w1s) +
      (size_t)e * kH * kI + (size_t)(bkb * 8) * kI + nb + bn0;
  char* bdstp = (char*)&Bs[which][0];
  f32x4 acc[2][2][4];
#pragma unroll
  for (int s = 0; s < 2; ++s)
#pragma unroll
    for (int mi = 0; mi < 2; ++mi)
#pragma unroll
      for (int ni = 0; ni < 4; ++ni)
#pragma unroll
        for (int r = 0; r < 4; ++r) acc[s][mi][ni][r] = 0.f;
  const int g = lane >> 4, r16 = lane & 15;
  for (int k0 = 0; k0 < kH; k0 += 32) {
    float4 a0 = *(const float4*)(arow + k0);
    float4 a1 = *(const float4*)(arow + k0 + 4);
    bf16x8 av;
    av[0] = f2bf(a0.x); av[1] = f2bf(a0.y); av[2] = f2bf(a0.z); av[3] = f2bf(a0.w);
    av[4] = f2bf(a1.x); av[5] = f2bf(a1.y); av[6] = f2bf(a1.z); av[7] = f2bf(a1.w);
    *(bf16x8*)&As[(akb * 64 + am) * 8] = av;
    {
      const float* bp = wbase + (size_t)k0 * kI;
      float4 v[8];
#pragma unroll
      for (int j = 0; j < 8; ++j) v[j] = *(const float4*)(bp + (size_t)j * kI);
      const float* vf = (const float*)v;
#pragma unroll
      for (int i = 0; i < 4; ++i) {
        bf16x8 w;
#pragma unroll
        for (int j = 0; j < 8; ++j) w[j] = f2bf(vf[j * 4 + i]);
        int n = bn0 + i;
        unsigned ba = (unsigned)((bkb * 128 + n) * 16) ^ ((((unsigned)n >> 3) & 7u) << 4);
        *(bf16x8*)(bdstp + ba) = w;
      }
    }
    __syncthreads();
    bf16x8 af[2], bfr[2][4];
#pragma unroll
    for (int mi = 0; mi < 2; ++mi)
      af[mi] = *(const bf16x8*)&As[(g * 64 + wr * 32 + mi * 16 + r16) * 8];
#pragma unroll
    for (int s = 0; s < 2; ++s)
#pragma unroll
      for (int ni = 0; ni < 4; ++ni) {
        int n = wc * 64 + ni * 16 + r16;
        unsigned ba = (unsigned)((g * 128 + n) * 16) ^ ((((unsigned)n >> 3) & 7u) << 4);
        bfr[s][ni] = *(const bf16x8*)((char*)&Bs[s][0] + ba);
      }
#pragma unroll
    for (int s = 0; s < 2; ++s)
#pragma unroll
      for (int mi = 0; mi < 2; ++mi)
#pragma unroll
        for (int ni = 0; ni < 4; ++ni)
          acc[s][mi][ni] = __builtin_amdgcn_mfma_f32_16x16x32_bf16(
              af[mi], bfr[s][ni], acc[s][mi][ni], 0, 0, 0);
    __syncthreads();
  }
#pragma unroll
  for (int mi = 0; mi < 2; ++mi)
#pragma unroll
    for (int ni = 0; ni < 4; ++ni)
#pragma unroll
      for (int r = 0; r < 4; ++r) {
        float h1 = acc[0][mi][ni][r];
        float h3 = acc[1][mi][ni][r];
        float y = h1 / (1.f + expf(-h1)) * h3;
        int m = wr * 32 + mi * 16 + g * 4 + r;
        int n = nb + wc * 64 + ni * 16 + r16;
        inter[(size_t)(slot0 + m) * kI + n] = f2bf(y);
      }
}

__global__ __launch_bounds__(256) void fb_mlp2(
    const short* __restrict__ inter, const float* __restrict__ w2s,
    const int* __restrict__ cnt, const int* __restrict__ off,
    const float* __restrict__ slot_weight, float* __restrict__ slot_out) {
  const int e = blockIdx.z;
  const int count = cnt[e];
  const int rb = blockIdx.y;
  if (rb * 64 >= count) return;
  const int slot0 = off[e] + rb * 64;
  const int nb = blockIdx.x * 128;
  __shared__ __align__(16) short As[8 * 64 * 8];
  __shared__ __align__(16) short Bs[8 * 128 * 8];
  const int tid  = threadIdx.x;
  const int lane = tid & 63;
  const int wid  = tid >> 6;
  const int wr = wid >> 1, wc = wid & 1;
  const int am = tid & 63, akb = tid >> 6;
  const short* arow = inter + (size_t)(slot0 + am) * kI;
  const int bn0 = (tid & 31) * 4;
  const int bkb = tid >> 5;
  const float* wbase = w2s + (size_t)e * kI * kH + (size_t)(bkb * 8) * kH + nb + bn0;
  f32x4 acc[2][4];
#pragma unroll
  for (int mi = 0; mi < 2; ++mi)
#pragma unroll
    for (int ni = 0; ni < 4; ++ni)
#pragma unroll
      for (int r = 0; r < 4; ++r) acc[mi][ni][r] = 0.f;
  const int g = lane >> 4, r16 = lane & 15;
  for (int k0 = 0; k0 < kI; k0 += 64) {
    bf16x8 x0 = *(const bf16x8*)(arow + k0 + akb * 8);
    bf16x8 x1 = *(const bf16x8*)(arow + k0 + (akb + 4) * 8);
    *(bf16x8*)&As[(akb * 64 + am) * 8] = x0;
    *(bf16x8*)&As[((akb + 4) * 64 + am) * 8] = x1;
    {
      const float* bp = wbase + (size_t)k0 * kH;
      float4 v[8];
#pragma unroll
      for (int j = 0; j < 8; ++j) v[j] = *(const float4*)(bp + (size_t)j * kH);
      const float* vf = (const float*)v;
#pragma unroll
      for (int i = 0; i < 4; ++i) {
        bf16x8 w;
#pragma unroll
        for (int j = 0; j < 8; ++j) w[j] = f2bf(vf[j * 4 + i]);
        int n = bn0 + i;
        unsigned ba = (unsigned)((bkb * 128 + n) * 16) ^ ((((unsigned)n >> 3) & 7u) << 4);
        *(bf16x8*)((char*)&Bs[0] + ba) = w;
      }
    }
    __syncthreads();
#pragma unroll
    for (int kk = 0; kk < 2; ++kk) {
      bf16x8 af[2], bfr[4];
#pragma unroll
      for (int mi = 0; mi < 2; ++mi)
        af[mi] = *(const bf16x8*)&As[((kk * 4 + g) * 64 + wr * 32 + mi * 16 + r16) * 8];
#pragma unroll
      for (int ni = 0; ni < 4; ++ni) {
        int n = wc * 64 + ni * 16 + r16;
        unsigned ba = (unsigned)(((kk * 4 + g) * 128 + n) * 16) ^ ((((unsigned)n >> 3) & 7u) << 4);
        bfr[ni] = *(const bf16x8*)((char*)&Bs[0] + ba);
      }
#pragma unroll
      for (int mi = 0; mi < 2; ++mi)
#pragma unroll
        for (int ni = 0; ni < 4; ++ni)
          acc[mi][ni] = __builtin_amdgcn_mfma_f32_16x16x32_bf16(
              af[mi], bfr[ni], acc[mi][ni], 0, 0, 0);
    }
    __syncthreads();
  }
  float sw[2][4];
#pragma unroll
  for (int mi = 0; mi < 2; ++mi)
#pragma unroll
    for (int r = 0; r < 4; ++r)
      sw[mi][r] = slot_weight[slot0 + wr * 32 + mi * 16 + g * 4 + r];
#pragma unroll
  for (int mi = 0; mi < 2; ++mi)
#pragma unroll
    for (int ni = 0; ni < 4; ++ni)
#pragma unroll
      for (int r = 0; r < 4; ++r) {
        int m = wr * 32 + mi * 16 + g * 4 + r;
        int n = nb + wc * 64 + ni * 16 + r16;
        slot_out[(size_t)(slot0 + m) * kH + n] = sw[mi][r] * acc[mi][ni][r];
      }
}

// ============================== launcher ====================================
extern "C" void kernel_launch(void* const* d_in, const int* in_sizes, int n_in,
                              void* d_out, int out_size, void* d_ws, size_t ws_size,
                              hipStream_t stream) {
  (void)in_sizes; (void)n_in; (void)out_size;
  const float* hs  = (const float*)d_in[0];
  const float* gw  = (const float*)d_in[1];
  const float* w1s = (const float*)d_in[2];
  const float* w2s = (const float*)d_in[3];
  const float* w3s = (const float*)d_in[4];
  float* out = (float*)d_out;
  char* ws = (char*)d_ws;

  // shared control region
  int*   cnt         = (int*)(ws + 0);
  int*   cursor      = (int*)(ws + 64);
  int*   off         = (int*)(ws + 128);
  int*   tok_e       = (int*)(ws + 256);
  float* tok_w       = (float*)(ws + 16640);
  int*   token_slots = (int*)(ws + 33024);
  int*   slot_token  = (int*)(ws + 49408);
  float* slot_weight = (float*)(ws + 68352);

  // fused-path layout (no w13t buffer): 128 MB total
  constexpr size_t OFF_HSB     = 131072;
  constexpr size_t OFF_INTER   = OFF_HSB + (size_t)kT * kH * 2;        // 4,325,376
  constexpr size_t OFF_W2T     = OFF_INTER + (size_t)kMaxSlots * kI * 2; // 42,074,112
  constexpr size_t OFF_SLOTOUT = OFF_W2T + (size_t)kNE * kH * kI * 2;  // 109,182,976
  constexpr size_t NEED        = OFF_SLOTOUT + (size_t)kMaxSlots * kH * 4; // 128,057,344

  hipMemsetAsync(ws, 0, 256, stream);

  if (ws_size >= NEED) {
    short* hsb      = (short*)(ws + OFF_HSB);
    short* inter    = (short*)(ws + OFF_INTER);
    short* w2t      = (short*)(ws + OFF_W2T);
    float* slot_out = (float*)(ws + OFF_SLOTOUT);

    router_convhs_kernel<<<kT / 4 + kT * kH / 8 / 256, 256, 0, stream>>>(
        hs, gw, cnt, tok_e, tok_w, hsb);
    offsets_kernel<<<1, 256, 0, stream>>>(cnt, off, slot_token, slot_weight);
    assign_kernel<<<kT / 256, 256, 0, stream>>>(tok_e, tok_w, off, cursor,
                                                slot_token, slot_weight, token_slots);
    g1_kernel<<<dim3(64, 16, 10), 256, 0, stream>>>(
        hsb, w1s, w3s, cnt, off, slot_token, inter, w2s, w2t);
    g2_kernel<<<1024, 256, 0, stream>>>(
        inter, w2t, cnt, off, slot_weight, slot_out);
    combine2_kernel<<<(kT * kH / 4) / 256, 256, 0, stream>>>(
        slot_out, token_slots, out);
  } else {
    // fallback: r1 layout
    float* slot_out = (float*)(ws + 131072);
    short* inter    = (short*)(ws + 131072 + 18874368);
    router_convhs_kernel<<<kT / 4, 256, 0, stream>>>(
        hs, gw, cnt, tok_e, tok_w, (short*)(ws + OFF_HSB));
    offsets_kernel<<<1, 256, 0, stream>>>(cnt, off, slot_token, slot_weight);
    assign_kernel<<<kT / 256, 256, 0, stream>>>(tok_e, tok_w, off, cursor,
                                                slot_token, slot_weight, token_slots);
    fb_mlp1<<<dim3(kI / 128, kT / 64, kNE), 256, 0, stream>>>(
        hs, w1s, w3s, cnt, off, slot_token, inter);
    fb_mlp2<<<dim3(kH / 128, kT / 64, kNE), 256, 0, stream>>>(
        inter, w2s, cnt, off, slot_weight, slot_out);
    combine2_kernel<<<(kT * kH / 4) / 256, 256, 0, stream>>>(
        slot_out, token_slots, out);
  }
}

// Round 15
// 334.889 us; speedup vs baseline: 2.1079x; 2.1079x over previous
//
#include <hip/hip_runtime.h>
#include <hip/hip_bf16.h>
#include <math.h>

// MoE: 8 experts, top-2, H=1024, I=4096, T=2048. f32 in/out, bf16 MFMA inside.
// Round 15: exact revert to r12 (best measured, 338us). r13 (reg-dbuf ILP) and
// r14 (launch_bounds(256,5) occupancy) both regressed via register spill:
// r13 FETCH +90MB; r14 VGPR 64->48, WRITE 573MB scratch, 706us. The compiler's
// natural allocation at (256,3) is the optimum of this structure.
constexpr int kNE = 8;
constexpr int kH  = 1024;
constexpr int kI  = 4096;
constexpr int kT  = 2048;
constexpr int kMaxSlots = kT * 2 + kNE * 64;   // 4608
constexpr int kSlotPad  = kMaxSlots + 128;

typedef short bf16x8 __attribute__((ext_vector_type(8)));
typedef float f32x4  __attribute__((ext_vector_type(4)));

__device__ __forceinline__ short f2bf(float f) {
  union { float f; unsigned u; } v; v.f = f;
  unsigned r = v.u + 0x7fffu + ((v.u >> 16) & 1u);   // RNE
  return (short)(r >> 16);
}

__device__ __forceinline__ int cvtpk(float lo, float hi) {
  int r;
  asm("v_cvt_pk_bf16_f32 %0, %1, %2" : "=v"(r) : "v"(lo), "v"(hi));
  return r;
}

__device__ __forceinline__ void gload16(const void* g, void* lds) {
  __builtin_amdgcn_global_load_lds(
      (const __attribute__((address_space(1))) void*)g,
      (__attribute__((address_space(3))) void*)lds, 16, 0, 0);
}

// ================= shared device building blocks ============================

// w2 transpose pair (two 128k x 64n tiles, 32KB LDS). dst: w2t [E][1024][4096].
__device__ __forceinline__ void w2t_pair(
    char* smemraw, int bt, const float* __restrict__ w2s,
    short* __restrict__ w2t) {
  float* tile = (float*)smemraw;
  const int tid = threadIdx.x;
#pragma unroll 1
  for (int s = 0; s < 2; ++s) {
    const int t = bt * 2 + s;                       // 0..4095
    const int e2 = t >> 9;
    const int r = t & 511;
    const int kbT = (r >> 4) * 128;
    const int nbT = (r & 15) * 64;
    const float* src = w2s + ((size_t)e2 * kI + kbT) * kH + nbT;
    if (s) __syncthreads();                         // LDS reuse WAR
#pragma unroll
    for (int p = 0; p < 8; ++p) {
      const int q = p * 256 + tid;
      const int k = q >> 4;
      const int nc = (q & 15) * 4;
      gload16(src + (size_t)k * kH + nc, (char*)tile + q * 16);
    }
    __syncthreads();                                // drains vmcnt
    const int c = tid & 63;
    const int kw = tid >> 6;
    short* drow = w2t + ((size_t)e2 * kH + nbT + c) * kI + kbT;
#pragma unroll
    for (int i = 0; i < 4; ++i) {
      const int kc = kw * 4 + i;
      bf16x8 v;
#pragma unroll
      for (int j = 0; j < 8; ++j) v[j] = f2bf(tile[(kc * 8 + j) * 64 + c]);
      *(bf16x8*)(drow + kc * 8) = v;
    }
  }
}

// g1 fused block: 128m x 128packed, 4 waves, BK=64, 32KB LDS.
// A: hsb bf16 via gload16 (unchanged). B: w1/w3 f32 -> reg cvt -> swizzled Bs.
__device__ __forceinline__ void g1_gemm_block(
    char* smem, int e, int rb, int nb,
    const short* __restrict__ hsb,
    const float* __restrict__ w1s, const float* __restrict__ w3s,
    const int* __restrict__ cnt, const int* __restrict__ off,
    const int* __restrict__ slot_token, short* __restrict__ inter) {
  const int count = cnt[e];
  if (rb * 128 >= count) return;
  const int slot0 = off[e] + rb * 128;
  const int mlim = ((count + 63) & ~63) - rb * 128;

  short* As = (short*)smem;                         // 16KB [row][slot]
  short* Bs = (short*)(smem + 16384);               // 16KB [c][swz slot]
  const int tid = threadIdx.x;
  const int l = tid & 63, w = tid >> 6;
  const int wr = w >> 1, wc = w & 1;

  // ---- A staging map (gload16, source-side swizzle; r5-r12 verified) ----
  const int srow = l >> 3;
  const int sch  = (l & 7) ^ srow;
  const short* aptr[4];
  unsigned sdstA[4];
#pragma unroll
  for (int i = 0; i < 4; ++i) {
    const int q = w * 4 + i;
    const int row = q * 8 + srow;
    int tok = slot_token[slot0 + row]; if (tok < 0) tok = 0;
    aptr[i] = hsb + (size_t)tok * kH + sch * 8;
    sdstA[i] = (unsigned)(q * 1024 + l * 16);
  }

  // ---- B staging map: thread -> 8k x 4 packed-n patch ----
  const int np = tid & 31;            // n-patch: packed cols np*4 .. np*4+3
  const int kp = tid >> 5;            // k-chunk 0..7 (k = kp*8 .. +7)
  const int selB = (np >> 3) & 1;     // 0 = w1, 1 = w3
  const int rcol = nb * 64 + (np >> 4) * 32 + (np & 7) * 4;   // real col base
  const float* bsrc = (selB ? w3s : w1s) +
      (size_t)e * kH * kI + (size_t)(kp * 8) * kI + rcol;
  unsigned bw[4];
#pragma unroll
  for (int j = 0; j < 4; ++j) {
    const int c = np * 4 + j;
    bw[j] = (unsigned)(c * 128 + (((kp ^ (c & 7) ^ ((c >> 3) & 7)) & 7) * 16));
  }

  f32x4 acc[4][4];
#pragma unroll
  for (int mi = 0; mi < 4; ++mi)
#pragma unroll
    for (int ni = 0; ni < 4; ++ni)
#pragma unroll
      for (int r = 0; r < 4; ++r) acc[mi][ni][r] = 0.f;

  const int r16 = l & 15, g = l >> 4;

  for (int t = 0; t < kH / 64; ++t) {
    const int k0 = t * 64;
    // ---- B loads first (f32, coalesced 256B segments) ----
    float4 bv[8];
#pragma unroll
    for (int q2 = 0; q2 < 8; ++q2)
      bv[q2] = *(const float4*)(bsrc + (size_t)(k0 + q2) * kI);
    // ---- A async gloads (stay in flight past the cvt) ----
#pragma unroll
    for (int i = 0; i < 4; ++i)
      gload16(aptr[i] + k0, (char*)As + sdstA[i]);
    // ---- convert 8k x 4n patch -> 4 bf16x8 granules ----
    int4 gi[4];
#define CVT_GRAN(J, SEL)                                     \
    gi[J].x = cvtpk(bv[0].SEL, bv[1].SEL);                   \
    gi[J].y = cvtpk(bv[2].SEL, bv[3].SEL);                   \
    gi[J].z = cvtpk(bv[4].SEL, bv[5].SEL);                   \
    gi[J].w = cvtpk(bv[6].SEL, bv[7].SEL);
    CVT_GRAN(0, x) CVT_GRAN(1, y) CVT_GRAN(2, z) CVT_GRAN(3, w)
#undef CVT_GRAN
    // prev iteration's MFMA completed at loop-end barrier -> safe to write
#pragma unroll
    for (int j = 0; j < 4; ++j)
      *(int4*)((char*)Bs + bw[j]) = gi[j];
    __syncthreads();                  // drains A gloads + ds_writes
#pragma unroll
    for (int kk = 0; kk < 2; ++kk) {
      const int chunk = kk * 4 + g;
      bf16x8 af[4], bf[4];
#pragma unroll
      for (int mi = 0; mi < 4; ++mi) {
        const int m = wr * 64 + mi * 16 + r16;
        af[mi] = *(const bf16x8*)((const char*)As + m * 128 + ((chunk ^ (m & 7)) * 16));
      }
#pragma unroll
      for (int ni = 0; ni < 4; ++ni) {
        const int c = wc * 64 + ni * 16 + r16;
        bf[ni] = *(const bf16x8*)((const char*)Bs +
                   c * 128 + ((chunk ^ (c & 7) ^ ((c >> 3) & 7)) * 16));
      }
#pragma unroll
      for (int mi = 0; mi < 4; ++mi)
#pragma unroll
        for (int ni = 0; ni < 4; ++ni)
          acc[mi][ni] = __builtin_amdgcn_mfma_f32_16x16x32_bf16(
              af[mi], bf[ni], acc[mi][ni], 0, 0, 0);
    }
    __syncthreads();
  }

  const int colb = (nb * 2 + wc) * 32;
#pragma unroll
  for (int mi = 0; mi < 4; ++mi)
#pragma unroll
    for (int r = 0; r < 4; ++r) {
      const int m = wr * 64 + mi * 16 + g * 4 + r;
      if (m < mlim) {
#pragma unroll
        for (int ni = 0; ni < 2; ++ni) {
          float h1 = acc[mi][ni][r];
          float h3 = acc[mi][ni + 2][r];
          float y = h1 / (1.f + expf(-h1)) * h3;
          inter[(size_t)(slot0 + m) * kI + colb + ni * 16 + r16] = f2bf(y);
        }
      }
    }
}

// ========================= small kernels ====================================

__global__ __launch_bounds__(256) void router_convhs_kernel(
    const float* __restrict__ hs, const float* __restrict__ gw,
    int* __restrict__ cnt, int* __restrict__ tok_e, float* __restrict__ tok_w,
    short* __restrict__ hsb) {
  if (blockIdx.x >= kT / 4) {
    const int idx = (blockIdx.x - kT / 4) * 256 + threadIdx.x;
    const float* p = hs + (size_t)idx * 8;
    float4 a = *(const float4*)p;
    float4 b = *(const float4*)(p + 4);
    bf16x8 w;
    w[0] = f2bf(a.x); w[1] = f2bf(a.y); w[2] = f2bf(a.z); w[3] = f2bf(a.w);
    w[4] = f2bf(b.x); w[5] = f2bf(b.y); w[6] = f2bf(b.z); w[7] = f2bf(b.w);
    *(bf16x8*)(hsb + (size_t)idx * 8) = w;
    return;
  }
  const int lane = threadIdx.x & 63;
  const int wid  = threadIdx.x >> 6;
  const int t = blockIdx.x * 4 + wid;
  const float* hrow = hs + (size_t)t * kH;
  float acc[kNE];
#pragma unroll
  for (int e = 0; e < kNE; ++e) acc[e] = 0.f;
  for (int i = lane; i < kH; i += 64) {
    float x = hrow[i];
    float4 g0 = *(const float4*)(gw + (size_t)i * kNE);
    float4 g1 = *(const float4*)(gw + (size_t)i * kNE + 4);
    acc[0] += x * g0.x; acc[1] += x * g0.y; acc[2] += x * g0.z; acc[3] += x * g0.w;
    acc[4] += x * g1.x; acc[5] += x * g1.y; acc[6] += x * g1.z; acc[7] += x * g1.w;
  }
#pragma unroll
  for (int o = 32; o; o >>= 1)
#pragma unroll
    for (int e = 0; e < kNE; ++e) acc[e] += __shfl_xor(acc[e], o);
  if (lane == 0) {
    int e0 = 0;
#pragma unroll
    for (int e = 1; e < kNE; ++e) if (acc[e] > acc[e0]) e0 = e;
    int e1 = (e0 == 0) ? 1 : 0;
#pragma unroll
    for (int e = 0; e < kNE; ++e) if (e != e0 && acc[e] > acc[e1]) e1 = e;
    float d  = acc[e1] - acc[e0];
    float w0 = 1.f / (1.f + expf(d));
    float w1 = 1.f / (1.f + expf(-d));
    atomicAdd(&cnt[e0], 1);
    atomicAdd(&cnt[e1], 1);
    tok_e[t * 2] = e0; tok_e[t * 2 + 1] = e1;
    tok_w[t * 2] = w0; tok_w[t * 2 + 1] = w1;
  }
}

__global__ __launch_bounds__(256) void offsets_kernel(
    const int* __restrict__ cnt, int* __restrict__ off,
    int* __restrict__ slot_token, float* __restrict__ slot_weight) {
  if (threadIdx.x == 0) {
    int o = 0;
#pragma unroll
    for (int e = 0; e < kNE; ++e) { off[e] = o; o += (cnt[e] + 63) & ~63; }
    off[kNE] = o;
  }
  for (int i = threadIdx.x; i < kSlotPad; i += 256) {
    slot_token[i]  = -1;
    slot_weight[i] = 0.f;
  }
}

__global__ __launch_bounds__(256) void assign_kernel(
    const int* __restrict__ tok_e, const float* __restrict__ tok_w,
    const int* __restrict__ off, int* __restrict__ cursor,
    int* __restrict__ slot_token, float* __restrict__ slot_weight,
    int* __restrict__ token_slots) {
  const int t = blockIdx.x * 256 + threadIdx.x;
  if (t >= kT) return;
#pragma unroll
  for (int k = 0; k < 2; ++k) {
    int e = tok_e[t * 2 + k];
    int pos = off[e] + atomicAdd(&cursor[e], 1);
    slot_token[pos]  = t;
    slot_weight[pos] = tok_w[t * 2 + k];
    token_slots[t * 2 + k] = pos;
  }
}

// g1 wrapper: z<8 fused GEMM; z=8,9 w2 transpose ride-along.
__global__ __launch_bounds__(256, 3) void g1_kernel(
    const short* __restrict__ hsb,
    const float* __restrict__ w1s, const float* __restrict__ w3s,
    const int* __restrict__ cnt, const int* __restrict__ off,
    const int* __restrict__ slot_token, short* __restrict__ inter,
    const float* __restrict__ w2s, short* __restrict__ w2t) {
  __shared__ __align__(16) char smem[32768];
  if (blockIdx.z >= 8) {
    w2t_pair(smem, ((blockIdx.z - 8) * 16 + blockIdx.y) * 64 + blockIdx.x,
             w2s, w2t);
    return;
  }
  g1_gemm_block(smem, blockIdx.z, blockIdx.y, blockIdx.x,
                hsb, w1s, w3s, cnt, off, slot_token, inter);
}

// --------- GEMM2: slot_out = w_slot * (inter @ w2), full-K, XCD-swizzled ----
__global__ __launch_bounds__(256, 3) void g2_kernel(
    const short* __restrict__ inter, const short* __restrict__ w2t,
    const int* __restrict__ cnt, const int* __restrict__ off,
    const float* __restrict__ slot_weight, float* __restrict__ slot_out) {
  const int bid = blockIdx.x;
  const int lid = (bid & 7) * 128 + (bid >> 3);
  const int nb = lid & 7;
  const int rb = (lid >> 3) & 15;
  const int e  = lid >> 7;
  const int count = cnt[e];
  if (rb * 128 >= count) return;
  const int slot0 = off[e] + rb * 128;
  const int mlim = ((count + 63) & ~63) - rb * 128;

  __shared__ __align__(16) short As[128 * 64];
  __shared__ __align__(16) short Bs[128 * 64];

  const int tid = threadIdx.x;
  const int l = tid & 63, w = tid >> 6;
  const int wr = w >> 1, wc = w & 1;

  const int srow = l >> 3;
  const int sch  = (l & 7) ^ srow;
  const short* aptr[4];
  const short* bptr[4];
  unsigned sdst[4];
#pragma unroll
  for (int i = 0; i < 4; ++i) {
    const int q = w * 4 + i;
    const int row = q * 8 + srow;
    int sr = slot0 + row; if (sr >= kMaxSlots) sr = kMaxSlots - 1;
    aptr[i] = inter + (size_t)sr * kI + sch * 8;
    bptr[i] = w2t + ((size_t)e * kH + nb * 128 + row) * kI + sch * 8;
    sdst[i] = (unsigned)(q * 1024 + l * 16);
  }

  f32x4 acc[4][4];
#pragma unroll
  for (int mi = 0; mi < 4; ++mi)
#pragma unroll
    for (int ni = 0; ni < 4; ++ni)
#pragma unroll
      for (int r = 0; r < 4; ++r) acc[mi][ni][r] = 0.f;

  const int r16 = l & 15, g = l >> 4;

  for (int t = 0; t < kI / 64; ++t) {
    const int k0 = t * 64;
#pragma unroll
    for (int i = 0; i < 4; ++i) {
      gload16(aptr[i] + k0, (char*)As + sdst[i]);
      gload16(bptr[i] + k0, (char*)Bs + sdst[i]);
    }
    __syncthreads();
#pragma unroll
    for (int kk = 0; kk < 2; ++kk) {
      const int chunk = kk * 4 + g;
      bf16x8 af[4], bf[4];
#pragma unroll
      for (int mi = 0; mi < 4; ++mi) {
        const int m = wr * 64 + mi * 16 + r16;
        af[mi] = *(const bf16x8*)((const char*)As + m * 128 + ((chunk ^ (m & 7)) * 16));
      }
#pragma unroll
      for (int ni = 0; ni < 4; ++ni) {
        const int n = wc * 64 + ni * 16 + r16;
        bf[ni] = *(const bf16x8*)((const char*)Bs + n * 128 + ((chunk ^ (n & 7)) * 16));
      }
#pragma unroll
      for (int mi = 0; mi < 4; ++mi)
#pragma unroll
        for (int ni = 0; ni < 4; ++ni)
          acc[mi][ni] = __builtin_amdgcn_mfma_f32_16x16x32_bf16(
              af[mi], bf[ni], acc[mi][ni], 0, 0, 0);
    }
    __syncthreads();
  }

#pragma unroll
  for (int mi = 0; mi < 4; ++mi)
#pragma unroll
    for (int r = 0; r < 4; ++r) {
      const int m = wr * 64 + mi * 16 + g * 4 + r;
      if (m < mlim) {
        const float sw = slot_weight[slot0 + m];
        const size_t orow = (size_t)(slot0 + m) * kH;
#pragma unroll
        for (int ni = 0; ni < 4; ++ni)
          slot_out[orow + nb * 128 + wc * 64 + ni * 16 + r16] =
              sw * acc[mi][ni][r];
      }
    }
}

// ------- combine: out[t] = slot_out[s0] + slot_out[s1] ----------------------
__global__ __launch_bounds__(256) void combine2_kernel(
    const float* __restrict__ slot_out, const int* __restrict__ token_slots,
    float* __restrict__ out) {
  int idx = blockIdx.x * 256 + threadIdx.x;
  int t = idx >> 8;
  int c = (idx & 255) * 4;
  int s0 = token_slots[t * 2];
  int s1 = token_slots[t * 2 + 1];
  float4 a = *(const float4*)(slot_out + (size_t)s0 * kH + c);
  float4 b = *(const float4*)(slot_out + (size_t)s1 * kH + c);
  float4 o;
  o.x = a.x + b.x; o.y = a.y + b.y; o.z = a.z + b.z; o.w = a.w + b.w;
  *(float4*)(out + (size_t)t * kH + c) = o;
}

// ===================== fallback path (r1, in-loop convert) ==================
__global__ __launch_bounds__(256) void fb_mlp1(
    const float* __restrict__ hs,
    const float* __restrict__ w1s, const float* __restrict__ w3s,
    const int* __restrict__ cnt, const int* __restrict__ off,
    const int* __restrict__ slot_token, short* __restrict__ inter) {
  const int e = blockIdx.z;
  const int count = cnt[e];
  const int rb = blockIdx.y;
  if (rb * 64 >= count) return;
  const int slot0 = off[e] + rb * 64;
  const int nb = blockIdx.x * 128;
  __shared__ __align__(16) short As[4 * 64 * 8];
  __shared__ __align__(16) short Bs[2][4 * 128 * 8];
  const int tid  = threadIdx.x;
  const int lane = tid & 63;
  const int wid  = tid >> 6;
  const int wr = wid >> 1, wc = wid & 1;
  const int am = tid & 63, akb = tid >> 6;
  int tok = slot_token[slot0 + am];
  if (tok < 0) tok = 0;
  const float* arow = hs + (size_t)tok * kH + akb * 8;
  const int which = tid >> 7;
  const int bn0 = (tid & 31) * 4;
  const int bkb = (tid >> 5) & 3;
  const float* wbase = (which ? w3s : w1s) +
      (size_t)e * kH * kI + (size_t)(bkb * 8) * kI + nb + bn0;
  char* bdstp = (char*)&Bs[which][0];
  f32x4 acc[2][2][4];
#pragma unroll
  for (int s = 0; s < 2; ++s)
#pragma unroll
    for (int mi = 0; mi < 2; ++mi)
#pragma unroll
      for (int ni = 0; ni < 4; ++ni)
#pragma unroll
        for (int r = 0; r < 4; ++r) acc[s][mi][ni][r] = 0.f;
  const int g = lane >> 4, r16 = lane & 15;
  for (int k0 = 0; k0 < kH; k0 += 32) {
    float4 a0 = *(const float4*)(arow + k0);
    float4 a1 = *(const float4*)(arow + k0 + 4);
    bf16x8 av;
    av[0] = f2bf(a0.x); av[1] = f2bf(a0.y); av[2] = f2bf(a0.z); av[3] = f2bf(a0.w);
    av[4] = f2bf(a1.x); av[5] = f2bf(a1.y); av[6] = f2bf(a1.z); av[7] = f2bf(a1.w);
    *(bf16x8*)&As[(akb * 64 + am) * 8] = av;
    {
      const float* bp = wbase + (size_t)k0 * kI;
      float4 v[8];
#pragma unroll
      for (int j = 0; j < 8; ++j) v[j] = *(const float4*)(bp + (size_t)j * kI);
      const float* vf = (const float*)v;
#pragma unroll
      for (int i = 0; i < 4; ++i) {
        bf16x8 w;
#pragma unroll
        for (int j = 0; j < 8; ++j) w[j] = f2bf(vf[j * 4 + i]);
        int n = bn0 + i;
        unsigned ba = (unsigned)((bkb * 128 + n) * 16) ^ ((((unsigned)n >> 3) & 7u) << 4);
        *(bf16x8*)(bdstp + ba) = w;
      }
    }
    __syncthreads();
    bf16x8 af[2], bfr[2][4];
#pragma unroll
    for (int mi = 0; mi < 2; ++mi)
      af[mi] = *(const bf16x8*)&As[(g * 64 + wr * 32 + mi * 16 + r16) * 8];
#pragma unroll
    for (int s = 0; s < 2; ++s)
#pragma unroll
      for (int ni = 0; ni < 4; ++ni) {
        int n = wc * 64 + ni * 16 + r16;
        unsigned ba = (unsigned)((g * 128 + n) * 16) ^ ((((unsigned)n >> 3) & 7u) << 4);
        bfr[s][ni] = *(const bf16x8*)((char*)&Bs[s][0] + ba);
      }
#pragma unroll
    for (int s = 0; s < 2; ++s)
#pragma unroll
      for (int mi = 0; mi < 2; ++mi)
#pragma unroll
        for (int ni = 0; ni < 4; ++ni)
          acc[s][mi][ni] = __builtin_amdgcn_mfma_f32_16x16x32_bf16(
              af[mi], bfr[s][ni], acc[s][mi][ni], 0, 0, 0);
    __syncthreads();
  }
#pragma unroll
  for (int mi = 0; mi < 2; ++mi)
#pragma unroll
    for (int ni = 0; ni < 4; ++ni)
#pragma unroll
      for (int r = 0; r < 4; ++r) {
        float h1 = acc[0][mi][ni][r];
        float h3 = acc[1][mi][ni][r];
        float y = h1 / (1.f + expf(-h1)) * h3;
        int m = wr * 32 + mi * 16 + g * 4 + r;
        int n = nb + wc * 64 + ni * 16 + r16;
        inter[(size_t)(slot0 + m) * kI + n] = f2bf(y);
      }
}

__global__ __launch_bounds__(256) void fb_mlp2(
    const short* __restrict__ inter, const float* __restrict__ w2s,
    const int* __restrict__ cnt, const int* __restrict__ off,
    const float* __restrict__ slot_weight, float* __restrict__ slot_out) {
  const int e = blockIdx.z;
  const int count = cnt[e];
  const int rb = blockIdx.y;
  if (rb * 64 >= count) return;
  const int slot0 = off[e] + rb * 64;
  const int nb = blockIdx.x * 128;
  __shared__ __align__(16) short As[8 * 64 * 8];
  __shared__ __align__(16) short Bs[8 * 128 * 8];
  const int tid  = threadIdx.x;
  const int lane = tid & 63;
  const int wid  = tid >> 6;
  const int wr = wid >> 1, wc = wid & 1;
  const int am = tid & 63, akb = tid >> 6;
  const short* arow = inter + (size_t)(slot0 + am) * kI;
  const int bn0 = (tid & 31) * 4;
  const int bkb = tid >> 5;
  const float* wbase = w2s + (size_t)e * kI * kH + (size_t)(bkb * 8) * kH + nb + bn0;
  f32x4 acc[2][4];
#pragma unroll
  for (int mi = 0; mi < 2; ++mi)
#pragma unroll
    for (int ni = 0; ni < 4; ++ni)
#pragma unroll
      for (int r = 0; r < 4; ++r) acc[mi][ni][r] = 0.f;
  const int g = lane >> 4, r16 = lane & 15;
  for (int k0 = 0; k0 < kI; k0 += 64) {
    bf16x8 x0 = *(const bf16x8*)(arow + k0 + akb * 8);
    bf16x8 x1 = *(const bf16x8*)(arow + k0 + (akb + 4) * 8);
    *(bf16x8*)&As[(akb * 64 + am) * 8] = x0;
    *(bf16x8*)&As[((akb + 4) * 64 + am) * 8] = x1;
    {
      const float* bp = wbase + (size_t)k0 * kH;
      float4 v[8];
#pragma unroll
      for (int j = 0; j < 8; ++j) v[j] = *(const float4*)(bp + (size_t)j * kH);
      const float* vf = (const float*)v;
#pragma unroll
      for (int i = 0; i < 4; ++i) {
        bf16x8 w;
#pragma unroll
        for (int j = 0; j < 8; ++j) w[j] = f2bf(vf[j * 4 + i]);
        int n = bn0 + i;
        unsigned ba = (unsigned)((bkb * 128 + n) * 16) ^ ((((unsigned)n >> 3) & 7u) << 4);
        *(bf16x8*)((char*)&Bs[0] + ba) = w;
      }
    }
    __syncthreads();
#pragma unroll
    for (int kk = 0; kk < 2; ++kk) {
      bf16x8 af[2], bfr[4];
#pragma unroll
      for (int mi = 0; mi < 2; ++mi)
        af[mi] = *(const bf16x8*)&As[((kk * 4 + g) * 64 + wr * 32 + mi * 16 + r16) * 8];
#pragma unroll
      for (int ni = 0; ni < 4; ++ni) {
        int n = wc * 64 + ni * 16 + r16;
        unsigned ba = (unsigned)(((kk * 4 + g) * 128 + n) * 16) ^ ((((unsigned)n >> 3) & 7u) << 4);
        bfr[ni] = *(const bf16x8*)((char*)&Bs[0] + ba);
      }
#pragma unroll
      for (int mi = 0; mi < 2; ++mi)
#pragma unroll
        for (int ni = 0; ni < 4; ++ni)
          acc[mi][ni] = __builtin_amdgcn_mfma_f32_16x16x32_bf16(
              af[mi], bfr[ni], acc[mi][ni], 0, 0, 0);
    }
    __syncthreads();
  }
  float sw[2][4];
#pragma unroll
  for (int mi = 0; mi < 2; ++mi)
#pragma unroll
    for (int r = 0; r < 4; ++r)
      sw[mi][r] = slot_weight[slot0 + wr * 32 + mi * 16 + g * 4 + r];
#pragma unroll
  for (int mi = 0; mi < 2; ++mi)
#pragma unroll
    for (int ni = 0; ni < 4; ++ni)
#pragma unroll
      for (int r = 0; r < 4; ++r) {
        int m = wr * 32 + mi * 16 + g * 4 + r;
        int n = nb + wc * 64 + ni * 16 + r16;
        slot_out[(size_t)(slot0 + m) * kH + n] = sw[mi][r] * acc[mi][ni][r];
      }
}

// ============================== launcher ====================================
extern "C" void kernel_launch(void* const* d_in, const int* in_sizes, int n_in,
                              void* d_out, int out_size, void* d_ws, size_t ws_size,
                              hipStream_t stream) {
  (void)in_sizes; (void)n_in; (void)out_size;
  const float* hs  = (const float*)d_in[0];
  const float* gw  = (const float*)d_in[1];
  const float* w1s = (const float*)d_in[2];
  const float* w2s = (const float*)d_in[3];
  const float* w3s = (const float*)d_in[4];
  float* out = (float*)d_out;
  char* ws = (char*)d_ws;

  // shared control region
  int*   cnt         = (int*)(ws + 0);
  int*   cursor      = (int*)(ws + 64);
  int*   off         = (int*)(ws + 128);
  int*   tok_e       = (int*)(ws + 256);
  float* tok_w       = (float*)(ws + 16640);
  int*   token_slots = (int*)(ws + 33024);
  int*   slot_token  = (int*)(ws + 49408);
  float* slot_weight = (float*)(ws + 68352);

  // fused-path layout (no w13t buffer): 128 MB total
  constexpr size_t OFF_HSB     = 131072;
  constexpr size_t OFF_INTER   = OFF_HSB + (size_t)kT * kH * 2;        // 4,325,376
  constexpr size_t OFF_W2T     = OFF_INTER + (size_t)kMaxSlots * kI * 2; // 42,074,112
  constexpr size_t OFF_SLOTOUT = OFF_W2T + (size_t)kNE * kH * kI * 2;  // 109,182,976
  constexpr size_t NEED        = OFF_SLOTOUT + (size_t)kMaxSlots * kH * 4; // 128,057,344

  hipMemsetAsync(ws, 0, 256, stream);

  if (ws_size >= NEED) {
    short* hsb      = (short*)(ws + OFF_HSB);
    short* inter    = (short*)(ws + OFF_INTER);
    short* w2t      = (short*)(ws + OFF_W2T);
    float* slot_out = (float*)(ws + OFF_SLOTOUT);

    router_convhs_kernel<<<kT / 4 + kT * kH / 8 / 256, 256, 0, stream>>>(
        hs, gw, cnt, tok_e, tok_w, hsb);
    offsets_kernel<<<1, 256, 0, stream>>>(cnt, off, slot_token, slot_weight);
    assign_kernel<<<kT / 256, 256, 0, stream>>>(tok_e, tok_w, off, cursor,
                                                slot_token, slot_weight, token_slots);
    g1_kernel<<<dim3(64, 16, 10), 256, 0, stream>>>(
        hsb, w1s, w3s, cnt, off, slot_token, inter, w2s, w2t);
    g2_kernel<<<1024, 256, 0, stream>>>(
        inter, w2t, cnt, off, slot_weight, slot_out);
    combine2_kernel<<<(kT * kH / 4) / 256, 256, 0, stream>>>(
        slot_out, token_slots, out);
  } else {
    // fallback: r1 layout
    float* slot_out = (float*)(ws + 131072);
    short* inter    = (short*)(ws + 131072 + 18874368);
    router_convhs_kernel<<<kT / 4, 256, 0, stream>>>(
        hs, gw, cnt, tok_e, tok_w, (short*)(ws + OFF_HSB));
    offsets_kernel<<<1, 256, 0, stream>>>(cnt, off, slot_token, slot_weight);
    assign_kernel<<<kT / 256, 256, 0, stream>>>(tok_e, tok_w, off, cursor,
                                                slot_token, slot_weight, token_slots);
    fb_mlp1<<<dim3(kI / 128, kT / 64, kNE), 256, 0, stream>>>(
        hs, w1s, w3s, cnt, off, slot_token, inter);
    fb_mlp2<<<dim3(kH / 128, kT / 64, kNE), 256, 0, stream>>>(
        inter, w2s, cnt, off, slot_weight, slot_out);
    combine2_kernel<<<(kT * kH / 4) / 256, 256, 0, stream>>>(
        slot_out, token_slots, out);
  }
}